// Round 9
// baseline (214.571 us; speedup 1.0000x reference)
//
#include <hip/hip_runtime.h>

typedef unsigned short u16;
typedef __bf16 bf16x8 __attribute__((ext_vector_type(8)));
typedef float f32x4 __attribute__((ext_vector_type(4)));

// B=2, S=2048, E=1024, HID=1024, HEADS=16 -> M=4096 rows, 3N=3072, 32 (h,b) pairs
static constexpr float SCALE2 = 0.022097086912079608f * 1.4426950408889634f;  // qk scale * log2(e)

__device__ __forceinline__ u16 f2b(float f) {
  union { float f; unsigned int i; } v; v.f = f;
  unsigned int r = v.i + 0x7fffu + ((v.i >> 16) & 1u);  // RNE
  return (u16)(r >> 16);
}
__device__ __forceinline__ float b2f(u16 u) {
  union { unsigned int i; float f; } v; v.i = ((unsigned int)u) << 16; return v.f;
}
// pack two f32 -> two bf16 in one u32 (HW cvt_pk if available)
__device__ __forceinline__ unsigned int pk2(float a, float b) {
#if __has_builtin(__builtin_amdgcn_cvt_pk_bf16_f32)
  auto v = __builtin_amdgcn_cvt_pk_bf16_f32(a, b);
  unsigned int u;
  __builtin_memcpy(&u, &v, 4);
  return u;
#else
  union { float f; unsigned int i; } x, y; x.f = a; y.f = b;
  return ((x.i + 0x8000u) >> 16) | ((y.i + 0x8000u) & 0xffff0000u);
#endif
}
__device__ __forceinline__ void async16(const u16* g, u16* l) {
  __builtin_amdgcn_global_load_lds((const __attribute__((address_space(1))) void*)g,
                                   (__attribute__((address_space(3))) void*)l,
                                   16, 0, 0);
}

// ---------------- LayerNorm: x[4096][1024] f32 -> xn bf16 ----------------
__global__ __launch_bounds__(256) void ln_kernel(const float* __restrict__ x,
                                                 const float* __restrict__ g,
                                                 const float* __restrict__ b,
                                                 u16* __restrict__ xn) {
  const int row = blockIdx.x;
  const int t = threadIdx.x;
  float4 v = *(const float4*)(x + (size_t)row * 1024 + t * 4);
  float s = v.x + v.y + v.z + v.w;
  float ss = v.x * v.x + v.y * v.y + v.z * v.z + v.w * v.w;
  for (int off = 32; off >= 1; off >>= 1) {
    s += __shfl_xor(s, off, 64);
    ss += __shfl_xor(ss, off, 64);
  }
  __shared__ float red[8];
  const int w = t >> 6;
  if ((t & 63) == 0) { red[w] = s; red[4 + w] = ss; }
  __syncthreads();
  s = red[0] + red[1] + red[2] + red[3];
  ss = red[4] + red[5] + red[6] + red[7];
  const float mu = s * (1.0f / 1024.0f);
  const float var = ss * (1.0f / 1024.0f) - mu * mu;
  const float inv = rsqrtf(var + 1e-5f);
  float4 gg = *(const float4*)(g + t * 4);
  float4 bb = *(const float4*)(b + t * 4);
  ushort4 o;
  o.x = f2b((v.x - mu) * inv * gg.x + bb.x);
  o.y = f2b((v.y - mu) * inv * gg.y + bb.y);
  o.z = f2b((v.z - mu) * inv * gg.z + bb.z);
  o.w = f2b((v.w - mu) * inv * gg.w + bb.w);
  *(ushort4*)(xn + (size_t)row * 1024 + t * 4) = o;
}

// --- merged transpose+cast: W1[1024][3072]->W1T[3072][1024], W2[1024][1024]->W2T ---
__global__ __launch_bounds__(256) void transpose2_k(const float* __restrict__ W1,
                                                    u16* __restrict__ W1T,
                                                    const float* __restrict__ W2,
                                                    u16* __restrict__ W2T) {
  const int z = blockIdx.z;
  if (z == 1 && blockIdx.x >= 16) return;
  const int C = z ? 1024 : 3072;
  const float* in = z ? W2 : W1;
  u16* out = z ? W2T : W1T;
  __shared__ u16 tile[64 * 72];
  const int c0 = blockIdx.x * 64, r0 = blockIdx.y * 64;
  const int t = threadIdx.x;
  const int row = t >> 2, cseg = t & 3;
  for (int it = 0; it < 4; it++) {
    float4 v = *(const float4*)&in[(size_t)(r0 + row) * C + c0 + it * 16 + cseg * 4];
    ushort4 o;
    o.x = f2b(v.x); o.y = f2b(v.y); o.z = f2b(v.z); o.w = f2b(v.w);
    *(ushort4*)&tile[row * 72 + it * 16 + cseg * 4] = o;
  }
  __syncthreads();
  const int orow = t >> 2, ch = t & 3;
  u16 vals[16];
  for (int j = 0; j < 16; j++) vals[j] = tile[(ch * 16 + j) * 72 + orow];
  u16* dp = out + (size_t)(c0 + orow) * 1024 + r0 + ch * 16;
  *(uint4*)&dp[0] = *(uint4*)&vals[0];
  *(uint4*)&dp[8] = *(uint4*)&vals[8];
}

// ------- GEMM (B^T input): C[M][N] = A[M][K] * Bt[N][K]^T + bias -------
// MT x 128 block tile, 4 waves (2x2), BK=32, 16x16x32 MFMA.
// MODE 0: C = float* row-major.
// MODE 1 (MT=128 only): coalesced bf16 stores into Qc/Kc/Vtmp [g][2048][64];
//   Q values are pre-scaled by SCALE2 (folded attention scale).
template <int MODE, int MT>
__global__ __launch_bounds__(256) void gemm_bt(const u16* __restrict__ A,
                                               const u16* __restrict__ Bt,
                                               const float* __restrict__ bias,
                                               float* __restrict__ C,
                                               int M, int N, int K,
                                               u16* __restrict__ Qc,
                                               u16* __restrict__ Kc,
                                               u16* __restrict__ Vtmp) {
  __shared__ __align__(16) u16 SMEM[8192];
  u16* As = SMEM;            // MT*32
  u16* Bs = SMEM + MT * 32;  // 128*32
  const int m0 = blockIdx.y * MT, n0 = blockIdx.x * 128;
  const int t = threadIdx.x, w = t >> 6, lane = t & 63;
  const int q = lane >> 4, l16 = lane & 15;
  const int wm = (w >> 1) * (MT / 2), wn = (w & 1) * 64;
  constexpr int NI = MT / 32;

  const int sc = (lane & 3) ^ ((lane >> 3) & 3);
  const u16* ap = A + (size_t)(m0 + w * 16 + (lane >> 2)) * K + sc * 8;
  const u16* bp = Bt + (size_t)(n0 + w * 16 + (lane >> 2)) * K + sc * 8;
  u16* lA = &As[w * 512];
  u16* lB = &Bs[w * 512];
  const int ac = q ^ ((l16 >> 1) & 3);

  f32x4 acc[NI][4];
  const f32x4 zero = {0.f, 0.f, 0.f, 0.f};
  for (int i = 0; i < NI; i++)
    for (int j = 0; j < 4; j++) acc[i][j] = zero;

  for (int k0 = 0; k0 < K; k0 += 32) {
    for (int i = 0; i < MT / 64; i++)
      async16(ap + (size_t)(i * 64) * K, lA + i * 2048);
    for (int i = 0; i < 2; i++)
      async16(bp + (size_t)(i * 64) * K, lB + i * 2048);
    ap += 32; bp += 32;
    __syncthreads();
    bf16x8 af[NI], bfr[4];
    for (int i = 0; i < NI; i++)
      af[i] = *(const bf16x8*)&As[(wm + i * 16 + l16) * 32 + ac * 8];
    for (int j = 0; j < 4; j++)
      bfr[j] = *(const bf16x8*)&Bs[(wn + j * 16 + l16) * 32 + ac * 8];
    for (int i = 0; i < NI; i++)
      for (int j = 0; j < 4; j++)
        acc[i][j] = __builtin_amdgcn_mfma_f32_16x16x32_bf16(af[i], bfr[j], acc[i][j], 0, 0, 0);
    __syncthreads();
  }

  if constexpr (MODE == 0) {
    for (int j = 0; j < 4; j++) {
      const int col = n0 + wn + j * 16 + l16;
      const float bv = bias[col];
      for (int i = 0; i < NI; i++) {
        const int rbase = m0 + wm + i * 16 + q * 4;
        for (int r = 0; r < 4; r++)
          C[(size_t)(rbase + r) * N + col] = acc[i][j][r] + bv;
      }
    }
  } else {
    // wave's 64-col segment: one type, fixed tcol.  seg = 64k -> typ = k%3, tcol = k/3.
    const int seg = n0 + wn;
    const int k64 = seg >> 6;
    const int tcol = k64 / 3;
    const int typ = k64 - tcol * 3;  // 0=Q,1=K,2=V
    u16* dst = (typ == 0) ? Qc : (typ == 1) ? Kc : Vtmp;
    const float qs = (typ == 0) ? SCALE2 : 1.0f;  // fold attention scale into Q
    const int gidx = m0 >> 7;
    u16* tw = &SMEM[w * 1280];  // [64 cols][20] u16, wave-private
    float bv[4];
    for (int j = 0; j < 4; j++) bv[j] = bias[seg + j * 16 + l16];
    __syncthreads();  // all waves done with As/Bs MFMA reads
    for (int i = 0; i < 4; i++) {
      for (int j = 0; j < 4; j++) {
        ushort4 pk;
        pk.x = f2b((acc[i][j][0] + bv[j]) * qs);
        pk.y = f2b((acc[i][j][1] + bv[j]) * qs);
        pk.z = f2b((acc[i][j][2] + bv[j]) * qs);
        pk.w = f2b((acc[i][j][3] + bv[j]) * qs);
        *(ushort4*)&tw[(j * 16 + l16) * 20 + q * 4] = pk;  // col-major, pad 20
      }
      const int r2 = lane >> 2;
      const int quarter = lane & 3;
      u16 vals[16];
      for (int c = 0; c < 16; c++)
        vals[c] = tw[(quarter * 16 + c) * 20 + r2];
      const int lr = wm + i * 16 + r2;
      const int s = (lr << 4) + tcol;
      u16* dp = dst + ((size_t)gidx * 2048 + s) * 64 + quarter * 16;
      *(uint4*)&dp[0] = *(uint4*)&vals[0];
      *(uint4*)&dp[8] = *(uint4*)&vals[8];
    }
  }
}

// ------- vtrans: Vtmp[g][2048][64] -> Vt[g][64][2048], 64x64 LDS tiles -------
__global__ __launch_bounds__(256) void vtrans(const u16* __restrict__ Vtmp,
                                              u16* __restrict__ Vt) {
  __shared__ __align__(16) u16 tile[64 * 64];  // XOR-swizzled chunks
  const int g = blockIdx.y, s0 = blockIdx.x * 64;
  const int t = threadIdx.x;
  const int row = t >> 3, ch = t & 7;
  for (int p = 0; p < 2; p++) {
    const int r = p * 32 + row;
    uint4 v = *(const uint4*)&Vtmp[((size_t)g * 2048 + s0 + r) * 64 + ch * 8];
    *(uint4*)&tile[r * 64 + ((ch ^ (r & 7)) * 8)] = v;
  }
  __syncthreads();
  const int d = t >> 2, scn = t & 3;
  u16 vals[16];
  for (int j2 = 0; j2 < 16; j2++) {
    const int s = scn * 16 + j2;
    vals[j2] = tile[s * 64 + (((d >> 3) ^ (s & 7)) * 8) + (d & 7)];
  }
  u16* dp = Vt + ((size_t)g * 64 + d) * 2048 + s0 + scn * 16;
  *(uint4*)&dp[0] = *(uint4*)&vals[0];
  *(uint4*)&dp[8] = *(uint4*)&vals[8];
}

// ------- flash attention, kv-split: 1 block per (g, q-tile 128, kv-half) -------
// grid (16, 32, 2) = 1024 blocks.  Each block sums over its 1024-kv half;
// no online max (scores bounded, exp2 safe), so halves combine by addition.
// LDS = 48 KB (3 blocks/CU): Ks 16K | Vs 16K | Ps 16K (PV in two in-wave
// phases reusing the Ps region; wave-private -> in-order DS, no barrier).
// Swizzles (c = 16-B chunk): Ks[s'][c] = K[s'][c ^ (s'&7)],
//   Vs[d][c] = V^T[d][c ^ (d&7)], Ps chunk c ^= (l16&3).
__global__ __launch_bounds__(256) void attn_kernel(const u16* __restrict__ Qc,
                                                   const u16* __restrict__ Kc,
                                                   const u16* __restrict__ Vt,
                                                   u16* __restrict__ Op,   // [2][4096][1024] bf16 (Oc layout)
                                                   float* __restrict__ lp) // [2][32*2048]
{
  __shared__ __align__(16) u16 LDS[24576];  // Ks [0,8192) | Vs [8192,16384) | Ps [16384,24576)
  u16* Ks = LDS;
  u16* Vs = LDS + 8192;
  u16* Ps = LDS + 16384;
  const int g = blockIdx.y;
  const int q0 = blockIdx.x * 128;
  const int half = blockIdx.z;
  const int t = threadIdx.x, w = t >> 6, lane = t & 63;
  const int q = lane >> 4, l16 = lane & 15;

  const u16* Qg = Qc + (size_t)g * 2048 * 64;
  const u16* Kg = Kc + (size_t)g * 2048 * 64 + (size_t)half * 1024 * 64;
  const u16* Vg = Vt + (size_t)g * 64 * 2048 + half * 1024;

  bf16x8 aq[2][2];  // B-frag: Q^T[d][qrow=l16] per strip (Q pre-scaled by SCALE2)
  for (int rt = 0; rt < 2; rt++)
    for (int ks = 0; ks < 2; ks++)
      aq[rt][ks] = *(const bf16x8*)&Qg[(size_t)(q0 + w * 32 + rt * 16 + l16) * 64 + ks * 32 + q * 8];

  f32x4 accO[2][4];  // O^T: row d=c*16+q*4+r, col qrow=l16, per strip
  const f32x4 zero = {0.f, 0.f, 0.f, 0.f};
  for (int rt = 0; rt < 2; rt++)
    for (int c = 0; c < 4; c++) accO[rt][c] = zero;
  f32x4 psv[2] = {zero, zero};  // per-lane partial l-sums

  const int kc = (lane & 7) ^ ((lane >> 3) & 7);
  const int vc = (lane & 15) ^ ((w * 4 + (lane >> 4)) & 7);
  const u16* kp = Kg + (size_t)(w * 8 + (lane >> 3)) * 64 + kc * 8;
  const u16* vp = Vg + (size_t)(w * 4 + (lane >> 4)) * 2048 + vc * 8;
  u16* lK = &Ks[w * 512];
  u16* lV = &Vs[w * 512];

  const int kch = q ^ (l16 & 7);
  const int pbase = w * 2048;   // per-wave Ps region (u16): 2 strips x 1024
  const int pxor = l16 & 3;

  for (int it = 0; it < 8; it++) {
    const int kt0 = it * 128;
    for (int i = 0; i < 4; i++) {
      async16(kp + (size_t)kt0 * 64 + i * 2048, lK + i * 2048);
      async16(vp + kt0 + (size_t)i * 32768, lV + i * 2048);
    }
    __syncthreads();  // staged data visible (and prev iter fully consumed)

    // S^T = K Q^T for both strips (Ks reads shared)
    f32x4 sa[2][8];
    for (int ct = 0; ct < 8; ct++) {
      bf16x8 bk0 = *(const bf16x8*)&Ks[(ct * 16 + l16) * 64 + kch * 8];
      bf16x8 bk1 = *(const bf16x8*)&Ks[(ct * 16 + l16) * 64 + (kch ^ 4) * 8];
      for (int rt = 0; rt < 2; rt++) {
        f32x4 a = zero;
        a = __builtin_amdgcn_mfma_f32_16x16x32_bf16(bk0, aq[rt][0], a, 0, 0, 0);
        a = __builtin_amdgcn_mfma_f32_16x16x32_bf16(bk1, aq[rt][1], a, 0, 0, 0);
        sa[rt][ct] = a;
      }
    }

    // two phases: {ct 0..3 -> PV ks2 0,1}, {ct 4..7 -> PV ks2 2,3}
    for (int ph = 0; ph < 2; ph++) {
      for (int rt = 0; rt < 2; rt++) {
        const int sbase = pbase + rt * 1024 + l16 * 32;
        for (int c4 = 0; c4 < 4; c4++) {
          const int ct = ph * 4 + c4;
          f32x4 p;
          for (int r = 0; r < 4; r++) p[r] = __builtin_amdgcn_exp2f(sa[rt][ct][r]);
          psv[rt] += p;
          uint2 pk;
          pk.x = pk2(p[0], p[1]);
          pk.y = pk2(p[2], p[3]);
          const int c2 = ((c4 & 1) * 2 + (q >> 1)) ^ pxor;
          *(uint2*)&Ps[sbase + (c4 >> 1) * 512 + c2 * 8 + (q & 1) * 4] = pk;
        }
      }
      for (int k2 = 0; k2 < 2; k2++) {
        const int ks2 = ph * 2 + k2;
        bf16x8 apf[2];
        for (int rt = 0; rt < 2; rt++)
          apf[rt] = *(const bf16x8*)&Ps[pbase + rt * 1024 + k2 * 512 + l16 * 32 + (q ^ pxor) * 8];
        for (int c = 0; c < 4; c++) {
          const int vch = (ks2 * 4 + q) ^ (l16 & 7);
          bf16x8 bv = *(const bf16x8*)&Vs[(c * 16 + l16) * 128 + vch * 8];
          for (int rt = 0; rt < 2; rt++)
            accO[rt][c] = __builtin_amdgcn_mfma_f32_16x16x32_bf16(bv, apf[rt], accO[rt][c], 0, 0, 0);
        }
      }
    }
    __syncthreads();  // all waves done with Ks/Vs before next stage
  }

  // epilogue: store UNNORMALIZED partial O (Oc layout) + partial l
  u16* Oh = Op + (size_t)half * 4194304;
  for (int rt = 0; rt < 2; rt++) {
    float lsum = psv[rt][0] + psv[rt][1] + psv[rt][2] + psv[rt][3];
    lsum += __shfl_xor(lsum, 16, 64);
    lsum += __shfl_xor(lsum, 32, 64);
    const int srow = q0 + w * 32 + rt * 16 + l16;
    if (q == 0) lp[half * 65536 + g * 2048 + srow] = lsum;
    const int orow = g * 128 + (srow >> 4);
    const int cbase = (srow & 15) * 64;
    for (int c = 0; c < 4; c++) {
      ushort4 o;
      o.x = f2b(accO[rt][c][0]);
      o.y = f2b(accO[rt][c][1]);
      o.z = f2b(accO[rt][c][2]);
      o.w = f2b(accO[rt][c][3]);
      *(ushort4*)&Oh[(size_t)orow * 1024 + cbase + c * 16 + q * 4] = o;
    }
  }
}

// ------- combine: Oc = (O1+O2) / (l1+l2), elementwise in Oc layout -------
__global__ __launch_bounds__(256) void combine_k(const u16* __restrict__ Op,
                                                 const float* __restrict__ lp,
                                                 u16* __restrict__ Oc) {
  const int idx4 = (blockIdx.x * 256 + threadIdx.x) * 4;
  const int orow = idx4 >> 10, col = idx4 & 1023;
  const int g = orow >> 7, shi = orow & 127, slo = col >> 6;
  const int s = g * 2048 + shi * 16 + slo;
  const float inv = 1.0f / (lp[s] + lp[65536 + s]);
  ushort4 a = *(const ushort4*)&Op[(size_t)idx4];
  ushort4 b = *(const ushort4*)&Op[(size_t)4194304 + idx4];
  ushort4 o;
  o.x = f2b((b2f(a.x) + b2f(b.x)) * inv);
  o.y = f2b((b2f(a.y) + b2f(b.y)) * inv);
  o.z = f2b((b2f(a.z) + b2f(b.z)) * inv);
  o.w = f2b((b2f(a.w) + b2f(b.w)) * inv);
  *(ushort4*)&Oc[(size_t)idx4] = o;
}

extern "C" void kernel_launch(void* const* d_in, const int* in_sizes, int n_in,
                              void* d_out, int out_size, void* d_ws, size_t ws_size,
                              hipStream_t stream) {
  (void)in_sizes; (void)n_in; (void)out_size; (void)ws_size;
  const float* x    = (const float*)d_in[0];
  const float* ln_g = (const float*)d_in[1];
  const float* ln_b = (const float*)d_in[2];
  const float* W1   = (const float*)d_in[3];
  const float* b1   = (const float*)d_in[4];
  const float* W2   = (const float*)d_in[5];
  const float* b2   = (const float*)d_in[6];

  char* ws = (char*)d_ws;
  u16* xn   = (u16*)(ws);                       // 8 MB [0,8M)   (reused as Oc)
  u16* W1T  = (u16*)(ws + ((size_t)8 << 20));   // 6 MB
  u16* W2T  = (u16*)(ws + ((size_t)14 << 20));  // 2 MB
  u16* Qc   = (u16*)(ws + ((size_t)16 << 20));  // 8 MB
  u16* Kc   = (u16*)(ws + ((size_t)24 << 20));  // 8 MB
  u16* Vtmp = (u16*)(ws + ((size_t)32 << 20));  // 8 MB (reused as O-partial half 0)
  u16* Vt   = (u16*)(ws + ((size_t)40 << 20));  // 8 MB
  u16* Op   = Vtmp;                             // half stride 8M elems -> half1 at [48M,56M)
  float* lp = (float*)(ws + ((size_t)56 << 20));// 512 KB (total 56.5 MB)
  u16* Oc   = xn;

  ln_kernel<<<dim3(4096), dim3(256), 0, stream>>>(x, ln_g, ln_b, xn);
  transpose2_k<<<dim3(48, 16, 2), dim3(256), 0, stream>>>(W1, W1T, W2, W2T);
  gemm_bt<1, 128><<<dim3(24, 32), dim3(256), 0, stream>>>(xn, W1T, b1, nullptr,
                                                          4096, 3072, 1024, Qc, Kc, Vtmp);
  vtrans<<<dim3(32, 32), dim3(256), 0, stream>>>(Vtmp, Vt);
  attn_kernel<<<dim3(16, 32, 2), dim3(256), 0, stream>>>(Qc, Kc, Vt, Op, lp);
  combine_k<<<dim3(4096), dim3(256), 0, stream>>>(Op, lp, Oc);
  gemm_bt<0, 64><<<dim3(8, 64), dim3(256), 0, stream>>>(Oc, W2T, b2, (float*)d_out,
                                                        4096, 1024, 1024, nullptr, nullptr, nullptr);
}

// Round 10
// 208.661 us; speedup vs baseline: 1.0283x; 1.0283x over previous
//
#include <hip/hip_runtime.h>

typedef unsigned short u16;
typedef __bf16 bf16x8 __attribute__((ext_vector_type(8)));
typedef float f32x4 __attribute__((ext_vector_type(4)));

// B=2, S=2048, E=1024, HID=1024, HEADS=16 -> M=4096 rows, 3N=3072, 32 (h,b) pairs
static constexpr float SCALE2 = 0.022097086912079608f * 1.4426950408889634f;  // qk scale * log2(e)

__device__ __forceinline__ u16 f2b(float f) {
  union { float f; unsigned int i; } v; v.f = f;
  unsigned int r = v.i + 0x7fffu + ((v.i >> 16) & 1u);  // RNE
  return (u16)(r >> 16);
}
// pack two f32 -> two bf16 in one u32 (HW cvt_pk if available)
__device__ __forceinline__ unsigned int pk2(float a, float b) {
#if __has_builtin(__builtin_amdgcn_cvt_pk_bf16_f32)
  auto v = __builtin_amdgcn_cvt_pk_bf16_f32(a, b);
  unsigned int u;
  __builtin_memcpy(&u, &v, 4);
  return u;
#else
  union { float f; unsigned int i; } x, y; x.f = a; y.f = b;
  return ((x.i + 0x8000u) >> 16) | ((y.i + 0x8000u) & 0xffff0000u);
#endif
}
__device__ __forceinline__ void async16(const u16* g, u16* l) {
  __builtin_amdgcn_global_load_lds((const __attribute__((address_space(1))) void*)g,
                                   (__attribute__((address_space(3))) void*)l,
                                   16, 0, 0);
}

// ---- fused pre-pass: LN (blocks 0..4095) + W1/W2 transpose+cast (4096..5119) ----
__global__ __launch_bounds__(256) void pre_kernel(const float* __restrict__ x,
                                                  const float* __restrict__ lg,
                                                  const float* __restrict__ lb,
                                                  u16* __restrict__ xn,
                                                  const float* __restrict__ W1,
                                                  u16* __restrict__ W1T,
                                                  const float* __restrict__ W2,
                                                  u16* __restrict__ W2T) {
  __shared__ __align__(16) u16 smem[64 * 72];
  const int bx = blockIdx.x;
  const int t = threadIdx.x;
  if (bx < 4096) {
    // -------- LayerNorm row bx --------
    float* red = (float*)smem;
    const int row = bx;
    float4 v = *(const float4*)(x + (size_t)row * 1024 + t * 4);
    float s = v.x + v.y + v.z + v.w;
    float ss = v.x * v.x + v.y * v.y + v.z * v.z + v.w * v.w;
    for (int off = 32; off >= 1; off >>= 1) {
      s += __shfl_xor(s, off, 64);
      ss += __shfl_xor(ss, off, 64);
    }
    const int w = t >> 6;
    if ((t & 63) == 0) { red[w] = s; red[4 + w] = ss; }
    __syncthreads();
    s = red[0] + red[1] + red[2] + red[3];
    ss = red[4] + red[5] + red[6] + red[7];
    const float mu = s * (1.0f / 1024.0f);
    const float var = ss * (1.0f / 1024.0f) - mu * mu;
    const float inv = rsqrtf(var + 1e-5f);
    float4 gg = *(const float4*)(lg + t * 4);
    float4 bb = *(const float4*)(lb + t * 4);
    ushort4 o;
    o.x = f2b((v.x - mu) * inv * gg.x + bb.x);
    o.y = f2b((v.y - mu) * inv * gg.y + bb.y);
    o.z = f2b((v.z - mu) * inv * gg.z + bb.z);
    o.w = f2b((v.w - mu) * inv * gg.w + bb.w);
    *(ushort4*)(xn + (size_t)row * 1024 + t * 4) = o;
    return;
  }
  // -------- weight transpose tile --------
  const float* in;
  u16* out;
  int C, c0, r0;
  if (bx < 4096 + 768) {
    const int idx = bx - 4096;
    C = 3072; in = W1; out = W1T;
    c0 = (idx % 48) * 64; r0 = (idx / 48) * 64;
  } else {
    const int idx = bx - 4864;
    C = 1024; in = W2; out = W2T;
    c0 = (idx % 16) * 64; r0 = (idx / 16) * 64;
  }
  const int row = t >> 2, cseg = t & 3;
  for (int it = 0; it < 4; it++) {
    float4 v = *(const float4*)&in[(size_t)(r0 + row) * C + c0 + it * 16 + cseg * 4];
    ushort4 o;
    o.x = f2b(v.x); o.y = f2b(v.y); o.z = f2b(v.z); o.w = f2b(v.w);
    *(ushort4*)&smem[row * 72 + it * 16 + cseg * 4] = o;
  }
  __syncthreads();
  const int orow = t >> 2, ch = t & 3;
  u16 vals[16];
  for (int j = 0; j < 16; j++) vals[j] = smem[(ch * 16 + j) * 72 + orow];
  u16* dp = out + (size_t)(c0 + orow) * 1024 + r0 + ch * 16;
  *(uint4*)&dp[0] = *(uint4*)&vals[0];
  *(uint4*)&dp[8] = *(uint4*)&vals[8];
}

// ------- GEMM (B^T input): C[M][N] = A[M][K] * Bt[N][K]^T + bias -------
// MT x 128 block tile, 4 waves (2x2), BK=32, 16x16x32 MFMA.
// MODE 0: C = float* row-major.
// MODE 1 (MT=128 only): coalesced bf16 stores into Qc/Kc/Vtmp [g][2048][64];
//   Q values pre-scaled by SCALE2 (folded attention scale).
template <int MODE, int MT>
__global__ __launch_bounds__(256) void gemm_bt(const u16* __restrict__ A,
                                               const u16* __restrict__ Bt,
                                               const float* __restrict__ bias,
                                               float* __restrict__ C,
                                               int M, int N, int K,
                                               u16* __restrict__ Qc,
                                               u16* __restrict__ Kc,
                                               u16* __restrict__ Vtmp) {
  __shared__ __align__(16) u16 SMEM[8192];
  u16* As = SMEM;            // MT*32
  u16* Bs = SMEM + MT * 32;  // 128*32
  const int m0 = blockIdx.y * MT, n0 = blockIdx.x * 128;
  const int t = threadIdx.x, w = t >> 6, lane = t & 63;
  const int q = lane >> 4, l16 = lane & 15;
  const int wm = (w >> 1) * (MT / 2), wn = (w & 1) * 64;
  constexpr int NI = MT / 32;

  const int sc = (lane & 3) ^ ((lane >> 3) & 3);
  const u16* ap = A + (size_t)(m0 + w * 16 + (lane >> 2)) * K + sc * 8;
  const u16* bp = Bt + (size_t)(n0 + w * 16 + (lane >> 2)) * K + sc * 8;
  u16* lA = &As[w * 512];
  u16* lB = &Bs[w * 512];
  const int ac = q ^ ((l16 >> 1) & 3);

  f32x4 acc[NI][4];
  const f32x4 zero = {0.f, 0.f, 0.f, 0.f};
  for (int i = 0; i < NI; i++)
    for (int j = 0; j < 4; j++) acc[i][j] = zero;

  for (int k0 = 0; k0 < K; k0 += 32) {
    for (int i = 0; i < MT / 64; i++)
      async16(ap + (size_t)(i * 64) * K, lA + i * 2048);
    for (int i = 0; i < 2; i++)
      async16(bp + (size_t)(i * 64) * K, lB + i * 2048);
    ap += 32; bp += 32;
    __syncthreads();
    bf16x8 af[NI], bfr[4];
    for (int i = 0; i < NI; i++)
      af[i] = *(const bf16x8*)&As[(wm + i * 16 + l16) * 32 + ac * 8];
    for (int j = 0; j < 4; j++)
      bfr[j] = *(const bf16x8*)&Bs[(wn + j * 16 + l16) * 32 + ac * 8];
    for (int i = 0; i < NI; i++)
      for (int j = 0; j < 4; j++)
        acc[i][j] = __builtin_amdgcn_mfma_f32_16x16x32_bf16(af[i], bfr[j], acc[i][j], 0, 0, 0);
    __syncthreads();
  }

  if constexpr (MODE == 0) {
    for (int j = 0; j < 4; j++) {
      const int col = n0 + wn + j * 16 + l16;
      const float bv = bias[col];
      for (int i = 0; i < NI; i++) {
        const int rbase = m0 + wm + i * 16 + q * 4;
        for (int r = 0; r < 4; r++)
          C[(size_t)(rbase + r) * N + col] = acc[i][j][r] + bv;
      }
    }
  } else {
    // wave's 64-col segment: one type, fixed tcol.  seg = 64k -> typ = k%3, tcol = k/3.
    const int seg = n0 + wn;
    const int k64 = seg >> 6;
    const int tcol = k64 / 3;
    const int typ = k64 - tcol * 3;  // 0=Q,1=K,2=V
    u16* dst = (typ == 0) ? Qc : (typ == 1) ? Kc : Vtmp;
    const float qs = (typ == 0) ? SCALE2 : 1.0f;  // fold attention scale into Q
    const int gidx = m0 >> 7;
    u16* tw = &SMEM[w * 1280];  // [64 cols][20] u16, wave-private
    float bv[4];
    for (int j = 0; j < 4; j++) bv[j] = bias[seg + j * 16 + l16];
    __syncthreads();  // all waves done with As/Bs MFMA reads
    for (int i = 0; i < 4; i++) {
      for (int j = 0; j < 4; j++) {
        ushort4 pk;
        pk.x = f2b((acc[i][j][0] + bv[j]) * qs);
        pk.y = f2b((acc[i][j][1] + bv[j]) * qs);
        pk.z = f2b((acc[i][j][2] + bv[j]) * qs);
        pk.w = f2b((acc[i][j][3] + bv[j]) * qs);
        *(ushort4*)&tw[(j * 16 + l16) * 20 + q * 4] = pk;  // col-major, pad 20
      }
      const int r2 = lane >> 2;
      const int quarter = lane & 3;
      u16 vals[16];
      for (int c = 0; c < 16; c++)
        vals[c] = tw[(quarter * 16 + c) * 20 + r2];
      const int lr = wm + i * 16 + r2;
      const int s = (lr << 4) + tcol;
      u16* dp = dst + ((size_t)gidx * 2048 + s) * 64 + quarter * 16;
      *(uint4*)&dp[0] = *(uint4*)&vals[0];
      *(uint4*)&dp[8] = *(uint4*)&vals[8];
    }
  }
}

// ------- vtrans: Vtmp[g][2048][64] -> Vt[g][64][2048], 64x64 LDS tiles -------
__global__ __launch_bounds__(256) void vtrans(const u16* __restrict__ Vtmp,
                                              u16* __restrict__ Vt) {
  __shared__ __align__(16) u16 tile[64 * 64];  // XOR-swizzled chunks
  const int g = blockIdx.y, s0 = blockIdx.x * 64;
  const int t = threadIdx.x;
  const int row = t >> 3, ch = t & 7;
  for (int p = 0; p < 2; p++) {
    const int r = p * 32 + row;
    uint4 v = *(const uint4*)&Vtmp[((size_t)g * 2048 + s0 + r) * 64 + ch * 8];
    *(uint4*)&tile[r * 64 + ((ch ^ (r & 7)) * 8)] = v;
  }
  __syncthreads();
  const int d = t >> 2, scn = t & 3;
  u16 vals[16];
  for (int j2 = 0; j2 < 16; j2++) {
    const int s = scn * 16 + j2;
    vals[j2] = tile[s * 64 + (((d >> 3) ^ (s & 7)) * 8) + (d & 7)];
  }
  u16* dp = Vt + ((size_t)g * 64 + d) * 2048 + s0 + scn * 16;
  *(uint4*)&dp[0] = *(uint4*)&vals[0];
  *(uint4*)&dp[8] = *(uint4*)&vals[8];
}

// ------- flash attention: 1 block per (g, q-tile 128), 4 waves -------
// Two 16-row q-strips per wave (Ks/Vs reads shared).  No online max
// (Q pre-scaled, scores bounded, exp2 safe); l-sum deferred to epilogue.
// Ps: padded stride-72 rows, phase-split (64 kv live at a time), NO XOR —
// bank math: row step 144 B = 4 banks -> b64 writes 2-way (free),
// b128 reads conflict-free.  LDS = 50 KB.
// Ks/Vs swizzles (c = 16-B chunk): Ks[s'][c]=K[s'][c^(s'&7)], Vs[d][c]=V^T[d][c^(d&7)].
__global__ __launch_bounds__(256) void attn_kernel(const u16* __restrict__ Qc,
                                                   const u16* __restrict__ Kc,
                                                   const u16* __restrict__ Vt,
                                                   u16* __restrict__ Oc) {
  __shared__ __align__(16) u16 LDS[25600];  // Ks [0,8192) | Vs [8192,16384) | Ps [16384,25600)
  u16* Ks = LDS;
  u16* Vs = LDS + 8192;
  u16* Ps = LDS + 16384;
  const int g = blockIdx.y;
  const int q0 = blockIdx.x * 128;
  const int t = threadIdx.x, w = t >> 6, lane = t & 63;
  const int q = lane >> 4, l16 = lane & 15;

  const u16* Qg = Qc + (size_t)g * 2048 * 64;
  const u16* Kg = Kc + (size_t)g * 2048 * 64;
  const u16* Vg = Vt + (size_t)g * 64 * 2048;

  bf16x8 aq[2][2];  // B-frag: Q^T[d][qrow=l16] per strip (pre-scaled by SCALE2)
  for (int rt = 0; rt < 2; rt++)
    for (int ks = 0; ks < 2; ks++)
      aq[rt][ks] = *(const bf16x8*)&Qg[(size_t)(q0 + w * 32 + rt * 16 + l16) * 64 + ks * 32 + q * 8];

  f32x4 accO[2][4];  // O^T: row d=c*16+q*4+r, col qrow=l16, per strip
  const f32x4 zero = {0.f, 0.f, 0.f, 0.f};
  for (int rt = 0; rt < 2; rt++)
    for (int c = 0; c < 4; c++) accO[rt][c] = zero;
  f32x4 psv[2] = {zero, zero};  // per-lane partial l-sums (deferred reduce)

  const int kc = (lane & 7) ^ ((lane >> 3) & 7);
  const int vc = (lane & 15) ^ ((w * 4 + (lane >> 4)) & 7);
  const u16* kp = Kg + (size_t)(w * 8 + (lane >> 3)) * 64 + kc * 8;
  const u16* vp = Vg + (size_t)(w * 4 + (lane >> 4)) * 2048 + vc * 8;
  u16* lK = &Ks[w * 512];
  u16* lV = &Vs[w * 512];

  const int kch = q ^ (l16 & 7);
  const int pb = w * 2304;  // per-wave Ps region: 2 strips x 16 rows x 72

  for (int it = 0; it < 16; it++) {
    const int kt0 = it * 128;
    for (int i = 0; i < 4; i++) {
      async16(kp + (size_t)kt0 * 64 + i * 2048, lK + i * 2048);
      async16(vp + kt0 + (size_t)i * 32768, lV + i * 2048);
    }
    __syncthreads();  // staged data visible (and prev iter fully consumed)

    // S^T = K Q^T for both strips (Ks reads shared)
    f32x4 sa[2][8];
    for (int ct = 0; ct < 8; ct++) {
      bf16x8 bk0 = *(const bf16x8*)&Ks[(ct * 16 + l16) * 64 + kch * 8];
      bf16x8 bk1 = *(const bf16x8*)&Ks[(ct * 16 + l16) * 64 + (kch ^ 4) * 8];
      for (int rt = 0; rt < 2; rt++) {
        f32x4 a = zero;
        a = __builtin_amdgcn_mfma_f32_16x16x32_bf16(bk0, aq[rt][0], a, 0, 0, 0);
        a = __builtin_amdgcn_mfma_f32_16x16x32_bf16(bk1, aq[rt][1], a, 0, 0, 0);
        sa[rt][ct] = a;
      }
    }

    // two phases: {ct 0..3 -> PV ks2 0,1}, {ct 4..7 -> PV ks2 2,3}
    // (Ps region wave-private; in-wave DS ordering makes write->read safe)
    for (int ph = 0; ph < 2; ph++) {
      for (int rt = 0; rt < 2; rt++) {
        u16* Pr = &Ps[pb + rt * 1152 + l16 * 72];
        for (int c4 = 0; c4 < 4; c4++) {
          const int ct = ph * 4 + c4;
          f32x4 p;
          for (int r = 0; r < 4; r++) p[r] = __builtin_amdgcn_exp2f(sa[rt][ct][r]);
          psv[rt] += p;
          uint2 pk;
          pk.x = pk2(p[0], p[1]);
          pk.y = pk2(p[2], p[3]);
          *(uint2*)&Pr[c4 * 16 + q * 4] = pk;
        }
      }
      for (int k2 = 0; k2 < 2; k2++) {
        const int ks2 = ph * 2 + k2;
        bf16x8 apf[2];
        for (int rt = 0; rt < 2; rt++)
          apf[rt] = *(const bf16x8*)&Ps[pb + rt * 1152 + l16 * 72 + k2 * 32 + q * 8];
        for (int c = 0; c < 4; c++) {
          const int vch = (ks2 * 4 + q) ^ (l16 & 7);
          bf16x8 bv = *(const bf16x8*)&Vs[(c * 16 + l16) * 128 + vch * 8];
          for (int rt = 0; rt < 2; rt++)
            accO[rt][c] = __builtin_amdgcn_mfma_f32_16x16x32_bf16(bv, apf[rt], accO[rt][c], 0, 0, 0);
        }
      }
    }
    __syncthreads();  // all waves done with Ks/Vs before next stage
  }

  // epilogue: reduce l across q-lanes once; normalize + store O^T
  for (int rt = 0; rt < 2; rt++) {
    float lsum = psv[rt][0] + psv[rt][1] + psv[rt][2] + psv[rt][3];
    lsum += __shfl_xor(lsum, 16, 64);
    lsum += __shfl_xor(lsum, 32, 64);
    const int srow = q0 + w * 32 + rt * 16 + l16;
    const int orow = g * 128 + (srow >> 4);
    const int cbase = (srow & 15) * 64;
    const float linv = 1.0f / lsum;
    for (int c = 0; c < 4; c++) {
      ushort4 o;
      o.x = f2b(accO[rt][c][0] * linv);
      o.y = f2b(accO[rt][c][1] * linv);
      o.z = f2b(accO[rt][c][2] * linv);
      o.w = f2b(accO[rt][c][3] * linv);
      *(ushort4*)&Oc[(size_t)orow * 1024 + cbase + c * 16 + q * 4] = o;
    }
  }
}

extern "C" void kernel_launch(void* const* d_in, const int* in_sizes, int n_in,
                              void* d_out, int out_size, void* d_ws, size_t ws_size,
                              hipStream_t stream) {
  (void)in_sizes; (void)n_in; (void)out_size; (void)ws_size;
  const float* x    = (const float*)d_in[0];
  const float* ln_g = (const float*)d_in[1];
  const float* ln_b = (const float*)d_in[2];
  const float* W1   = (const float*)d_in[3];
  const float* b1   = (const float*)d_in[4];
  const float* W2   = (const float*)d_in[5];
  const float* b2   = (const float*)d_in[6];

  char* ws = (char*)d_ws;
  u16* xn   = (u16*)(ws);                       // 8 MB [0,8M)  (reused as Oc)
  u16* W1T  = (u16*)(ws + ((size_t)8 << 20));   // 6 MB
  u16* W2T  = (u16*)(ws + ((size_t)14 << 20));  // 2 MB
  u16* Qc   = (u16*)(ws + ((size_t)16 << 20));  // 8 MB
  u16* Kc   = (u16*)(ws + ((size_t)24 << 20));  // 8 MB
  u16* Vtmp = (u16*)(ws + ((size_t)32 << 20));  // 8 MB
  u16* Vt   = (u16*)(ws + ((size_t)40 << 20));  // 8 MB (total 48 MB)
  u16* Oc   = xn;

  pre_kernel<<<dim3(5120), dim3(256), 0, stream>>>(x, ln_g, ln_b, xn, W1, W1T, W2, W2T);
  gemm_bt<1, 128><<<dim3(24, 32), dim3(256), 0, stream>>>(xn, W1T, b1, nullptr,
                                                          4096, 3072, 1024, Qc, Kc, Vtmp);
  vtrans<<<dim3(32, 32), dim3(256), 0, stream>>>(Vtmp, Vt);
  attn_kernel<<<dim3(16, 32), dim3(256), 0, stream>>>(Qc, Kc, Vt, Oc);
  gemm_bt<0, 64><<<dim3(8, 64), dim3(256), 0, stream>>>(Oc, W2T, b2, (float*)d_out,
                                                        4096, 1024, 1024, nullptr, nullptr, nullptr);
}